// Round 4
// baseline (208.683 us; speedup 1.0000x reference)
//
#include <hip/hip_runtime.h>
#include <cstdint>
#include <cstddef>

// LSTM cell: B=4096, IN=1024, H=1024
//   ifgo = h @ Wh^T + bh + x @ Wx^T    [4096 x 4096]
//   i,f,g,o = split(ifgo); c' = sig(f)*c + sig(i)*tanh(g); h' = o*tanh(c')
//
// Pipeline (2 dispatches):
//   1. convert: fp32->bf16 into INTERLEAVED K=2048 layout:
//        A_cat[m][0:1024]=h[m], [1024:2048]=x[m]          (4096 x 2048)
//        W_cat[p][0:1024]=Wh[L], [1024:2048]=Wx[L]        (4096 x 2048)
//      with W rows permuted p = ((j>>4)<<6)|(gate<<4)|(j&15) so each wave's
//      64 output columns hold all 4 gates of 16 consecutive j.
//   2. gemm: m97-structure bf16 MFMA (128x128 tile, BK=32, global_load_lds
//      width=16), flat K-loop (no segment branch), XCD-aware tile swizzle,
//      fused fast-math gate epilogue writing h_next/c_next directly.

#define NB   4096      // batch
#define KH   1024      // H (== IN)
#define KK   2048      // concatenated K
#define ARR_ELEMS 4194304  // 4096*1024

typedef __bf16 bf16x8 __attribute__((ext_vector_type(8)));
typedef float  f32x4  __attribute__((ext_vector_type(4)));

__device__ inline unsigned short f2bf(float f) {
    union { float f; unsigned int u; } v; v.f = f;
    unsigned int u = v.u;
    u += 0x7FFFu + ((u >> 16) & 1u);   // RNE
    return (unsigned short)(u >> 16);
}

// fast gates: v_exp_f32 + v_rcp_f32, no branches
__device__ inline float fsig(float v)  { return __builtin_amdgcn_rcpf(1.f + __expf(-v)); }
__device__ inline float ftanh(float v) { return 1.f - 2.f * __builtin_amdgcn_rcpf(1.f + __expf(2.f * v)); }

// ---------------------------------------------------------------- convert ---
// ws layout (bf16): A_cat (8M elems) | W_cat (8M elems)
__global__ void convert_kernel(const float* __restrict__ h, const float* __restrict__ x,
                               const float* __restrict__ Wh, const float* __restrict__ Wx,
                               unsigned short* __restrict__ A, unsigned short* __restrict__ W) {
    int idx = blockIdx.x * 256 + threadIdx.x;       // 0 .. 4M-1, 4 floats each
    int arr = idx >> 20;                            // which source array
    int off = (idx & 0xFFFFF) << 2;                 // element offset within array
    const float* src = (arr == 0) ? h : (arr == 1) ? x : (arr == 2) ? Wh : Wx;
    float4 v = *(const float4*)(src + off);
    unsigned int lo = (unsigned int)f2bf(v.x) | ((unsigned int)f2bf(v.y) << 16);
    unsigned int hi = (unsigned int)f2bf(v.z) | ((unsigned int)f2bf(v.w) << 16);
    uint2 packed; packed.x = lo; packed.y = hi;

    int row = off >> 10;                            // logical row
    int col = off & 1023;
    unsigned short* dst;
    size_t dstOff;
    if (arr < 2) {                                  // A_cat: [h | x] per row
        dst = A;
        dstOff = (size_t)row * KK + (arr == 1 ? 1024 : 0) + col;
    } else {                                        // W_cat: permuted rows, [Wh | Wx]
        int g = row >> 10, j = row & 1023;
        int p = ((j >> 4) << 6) | (g << 4) | (j & 15);
        dst = W;
        dstOff = (size_t)p * KK + (arr == 3 ? 1024 : 0) + col;
    }
    *(uint2*)(dst + dstOff) = packed;
}

// ------------------------------------------------------------------- gemm ---
// 256 threads (4 waves), each wave 64x64 via 4x4 MFMA 16x16x32 bf16.
__global__ void gemm_kernel(const unsigned short* __restrict__ A,
                            const unsigned short* __restrict__ W,
                            const float* __restrict__ bh,
                            const float* __restrict__ c,
                            float* __restrict__ out) {
    __shared__ __align__(16) unsigned short As[128 * 32];
    __shared__ __align__(16) unsigned short Bs[128 * 32];

    const int tid  = threadIdx.x;
    const int wave = tid >> 6;
    const int lane = tid & 63;

    // XCD-aware swizzle: blocks land on XCD (blk % 8); give each XCD a 4-row
    // A band (2 MB, L2-resident) and reuse each B tile 4x consecutively.
    const int blk   = blockIdx.y * 32 + blockIdx.x;   // 0..1023
    const int xcd   = blk & 7;
    const int sidx  = blk >> 3;                       // 0..127 within XCD
    const int tileM = xcd * 4 + (sidx & 3);           // 0..31
    const int tileN = sidx >> 2;                      // 0..31

    // staging addressing: lane writes LDS at waveBase + lane*16B (wave-uniform rule)
    const int stRow  = wave * 16 + (lane >> 2);   // 0..63 for issue 0
    const int stColE = (lane & 3) * 8;            // element offset in K
    const unsigned short* ga = A + (size_t)(tileM * 128 + stRow) * KK + stColE;
    const unsigned short* gb = W + (size_t)(tileN * 128 + stRow) * KK + stColE;

    // compute-side fragment addressing
    const int mBase = (wave >> 1) * 64;
    const int nBase = (wave & 1) * 64;
    const int fr = lane & 15;            // row within 16x16 tile (A/B operand)
    const int fk = (lane >> 4) * 8;      // k offset within BK

    f32x4 acc[4][4] = {};

    for (int kt = 0; kt < 64; ++kt, ga += 32, gb += 32) {
        __builtin_amdgcn_global_load_lds(
            (const __attribute__((address_space(1))) void*)ga,
            (__attribute__((address_space(3))) void*)(As + wave * 512), 16, 0, 0);
        __builtin_amdgcn_global_load_lds(
            (const __attribute__((address_space(1))) void*)(ga + 64 * KK),
            (__attribute__((address_space(3))) void*)(As + 2048 + wave * 512), 16, 0, 0);
        __builtin_amdgcn_global_load_lds(
            (const __attribute__((address_space(1))) void*)gb,
            (__attribute__((address_space(3))) void*)(Bs + wave * 512), 16, 0, 0);
        __builtin_amdgcn_global_load_lds(
            (const __attribute__((address_space(1))) void*)(gb + 64 * KK),
            (__attribute__((address_space(3))) void*)(Bs + 2048 + wave * 512), 16, 0, 0);

        __syncthreads();

        bf16x8 a[4], b[4];
        #pragma unroll
        for (int i = 0; i < 4; ++i)
            a[i] = *(const bf16x8*)(As + (mBase + i * 16 + fr) * 32 + fk);
        #pragma unroll
        for (int j = 0; j < 4; ++j)
            b[j] = *(const bf16x8*)(Bs + (nBase + j * 16 + fr) * 32 + fk);

        #pragma unroll
        for (int i = 0; i < 4; ++i)
            #pragma unroll
            for (int j = 0; j < 4; ++j)
                acc[i][j] = __builtin_amdgcn_mfma_f32_16x16x32_bf16(a[i], b[j], acc[i][j], 0, 0, 0);

        __syncthreads();
    }

    // ---- fused LSTM gate epilogue -------------------------------------
    // Physical col of acc[i][k][r] = tileN*128 + nBase + 16k + (lane&15);
    // with the W-row permutation: gate = k, logical j = 16*q + (lane&15),
    // q = tileN*2 + (wave&1).
    const int j = ((tileN * 2 + (wave & 1)) << 4) | (lane & 15);
    const float bi = bh[j];
    const float bf = bh[j + 1024];
    const float bg = bh[j + 2048];
    const float bo = bh[j + 3072];

    const int row0 = tileM * 128 + mBase + (lane >> 4) * 4;

    // batch all c loads first: one latency exposure, not 16 serialized ones
    float cv[4][4];
    #pragma unroll
    for (int i = 0; i < 4; ++i)
        #pragma unroll
        for (int r = 0; r < 4; ++r)
            cv[i][r] = c[(size_t)(row0 + i * 16 + r) * KH + j];

    #pragma unroll
    for (int i = 0; i < 4; ++i) {
        #pragma unroll
        for (int r = 0; r < 4; ++r) {
            const size_t idx = (size_t)(row0 + i * 16 + r) * KH + j;
            float iv = fsig(acc[i][0][r] + bi);
            float fv = fsig(acc[i][1][r] + bf);
            float gv = ftanh(acc[i][2][r] + bg);
            float ov = fsig(acc[i][3][r] + bo);
            float cn = fv * cv[i][r] + iv * gv;
            float hn = ov * ftanh(cn);
            out[idx] = hn;
            out[(size_t)ARR_ELEMS + idx] = cn;
        }
    }
}

// ----------------------------------------------------------------- launch ---
extern "C" void kernel_launch(void* const* d_in, const int* in_sizes, int n_in,
                              void* d_out, int out_size, void* d_ws, size_t ws_size,
                              hipStream_t stream) {
    const float* x  = (const float*)d_in[0];
    const float* h  = (const float*)d_in[1];
    const float* c  = (const float*)d_in[2];
    const float* Wh = (const float*)d_in[3];
    const float* bh = (const float*)d_in[4];
    const float* Wx = (const float*)d_in[5];
    float* out = (float*)d_out;

    unsigned short* ws   = (unsigned short*)d_ws;
    unsigned short* Acat = ws;                            // [4096 x 2048] bf16
    unsigned short* Wcat = ws + 2 * (size_t)ARR_ELEMS;    // [4096 x 2048] bf16 (rows permuted)

    convert_kernel<<<16384, 256, 0, stream>>>(h, x, Wh, Wx, Acat, Wcat);
    dim3 grid(32, 32);
    gemm_kernel<<<grid, 256, 0, stream>>>(Acat, Wcat, bh, c, out);
}

// Round 5
// 202.424 us; speedup vs baseline: 1.0309x; 1.0309x over previous
//
#include <hip/hip_runtime.h>
#include <cstdint>
#include <cstddef>

// LSTM cell: B=4096, IN=1024, H=1024
//   ifgo = h @ Wh^T + bh + x @ Wx^T    [4096 x 4096]
//   i,f,g,o = split(ifgo); c' = sig(f)*c + sig(i)*tanh(g); h' = o*tanh(c')
//
// Pipeline (2 dispatches):
//   1. convert: fp32->bf16 into interleaved K=2048 layout (A_cat=[h|x],
//      W_cat=[Wh|Wx]) with W rows permuted p=((j>>4)<<6)|(gate<<4)|(j&15)
//      so each wave's 64 output columns hold all 4 gates of 16 consecutive j.
//   2. gemm: bf16 MFMA, 128x128 tile, BK=64 staged as TWO 128x32 LDS panels
//      (halves barrier count vs BK=32; LDS 32KB, occupancy is work-capped at
//      4 blocks/CU so no occupancy loss), global_load_lds width=16, fused
//      fast-math gate epilogue writing h_next/c_next directly.

#define NB   4096      // batch
#define KH   1024      // H (== IN)
#define KK   2048      // concatenated K
#define ARR_ELEMS 4194304  // 4096*1024

typedef __bf16 bf16x8 __attribute__((ext_vector_type(8)));
typedef float  f32x4  __attribute__((ext_vector_type(4)));

__device__ inline unsigned short f2bf(float f) {
    union { float f; unsigned int u; } v; v.f = f;
    unsigned int u = v.u;
    u += 0x7FFFu + ((u >> 16) & 1u);   // RNE
    return (unsigned short)(u >> 16);
}

// fast gates: v_exp_f32 + v_rcp_f32, no branches
__device__ inline float fsig(float v)  { return __builtin_amdgcn_rcpf(1.f + __expf(-v)); }
__device__ inline float ftanh(float v) { return 1.f - 2.f * __builtin_amdgcn_rcpf(1.f + __expf(2.f * v)); }

// ---------------------------------------------------------------- convert ---
// ws layout (bf16): A_cat (8M elems) | W_cat (8M elems)
__global__ void convert_kernel(const float* __restrict__ h, const float* __restrict__ x,
                               const float* __restrict__ Wh, const float* __restrict__ Wx,
                               unsigned short* __restrict__ A, unsigned short* __restrict__ W) {
    int idx = blockIdx.x * 256 + threadIdx.x;       // 0 .. 4M-1, 4 floats each
    int arr = idx >> 20;                            // which source array
    int off = (idx & 0xFFFFF) << 2;                 // element offset within array
    const float* src = (arr == 0) ? h : (arr == 1) ? x : (arr == 2) ? Wh : Wx;
    float4 v = *(const float4*)(src + off);
    unsigned int lo = (unsigned int)f2bf(v.x) | ((unsigned int)f2bf(v.y) << 16);
    unsigned int hi = (unsigned int)f2bf(v.z) | ((unsigned int)f2bf(v.w) << 16);
    uint2 packed; packed.x = lo; packed.y = hi;

    int row = off >> 10;                            // logical row
    int col = off & 1023;
    unsigned short* dst;
    size_t dstOff;
    if (arr < 2) {                                  // A_cat: [h | x] per row
        dst = A;
        dstOff = (size_t)row * KK + (arr == 1 ? 1024 : 0) + col;
    } else {                                        // W_cat: permuted rows, [Wh | Wx]
        int g = row >> 10, j = row & 1023;
        int p = ((j >> 4) << 6) | (g << 4) | (j & 15);
        dst = W;
        dstOff = (size_t)p * KK + (arr == 3 ? 1024 : 0) + col;
    }
    *(uint2*)(dst + dstOff) = packed;
}

// ------------------------------------------------------------------- gemm ---
// 256 threads (4 waves), each wave 64x64 via 4x4 MFMA 16x16x32 bf16.
// BK=64 per iteration, staged as two 128x32 panels (panel s = K-half s),
// so fragment addressing within a panel is identical to the BK=32 version.
__global__ void gemm_kernel(const unsigned short* __restrict__ A,
                            const unsigned short* __restrict__ W,
                            const float* __restrict__ bh,
                            const float* __restrict__ c,
                            float* __restrict__ out) {
    __shared__ __align__(16) unsigned short As[2 * 128 * 32];
    __shared__ __align__(16) unsigned short Bs[2 * 128 * 32];

    const int tid  = threadIdx.x;
    const int wave = tid >> 6;
    const int lane = tid & 63;
    const int tileN = blockIdx.x;   // 0..31  (output cols / 128)
    const int tileM = blockIdx.y;   // 0..31  (output rows / 128)

    // staging: issue i (i=0..3) covers rows (i&1)*64 + wave*16 + (lane>>2),
    // K-cols (i>>1)*32 + (lane&3)*8.  LDS chunk = i*256 + wave*64 + lane,
    // byte offset = chunk*16  -> uniform base (i*2048 + wave*512 elems) + lane*16B.
    const int stRow  = wave * 16 + (lane >> 2);   // 0..63
    const int stColE = (lane & 3) * 8;            // 0..24
    const unsigned short* gaBase = A + (size_t)(tileM * 128 + stRow) * KK + stColE;
    const unsigned short* gbBase = W + (size_t)(tileN * 128 + stRow) * KK + stColE;

    // compute-side fragment addressing
    const int mBase = (wave >> 1) * 64;
    const int nBase = (wave & 1) * 64;
    const int fr = lane & 15;            // row within 16x16 tile (A/B operand)
    const int fk = (lane >> 4) * 8;      // k offset within a 32-K panel

    f32x4 acc[4][4] = {};

    for (int kt = 0; kt < 32; ++kt) {
        const unsigned short* ga = gaBase + kt * 64;
        const unsigned short* gb = gbBase + kt * 64;
        #pragma unroll
        for (int i = 0; i < 4; ++i) {
            const int gOff = (i & 1) * 64 * KK + (i >> 1) * 32;   // row / K-panel select
            const int lOff = i * 2048 + wave * 512;               // LDS elems, wave-uniform
            __builtin_amdgcn_global_load_lds(
                (const __attribute__((address_space(1))) void*)(ga + gOff),
                (__attribute__((address_space(3))) void*)(As + lOff), 16, 0, 0);
            __builtin_amdgcn_global_load_lds(
                (const __attribute__((address_space(1))) void*)(gb + gOff),
                (__attribute__((address_space(3))) void*)(Bs + lOff), 16, 0, 0);
        }

        __syncthreads();

        #pragma unroll
        for (int s = 0; s < 2; ++s) {            // the two 32-K panels
            bf16x8 a[4], b[4];
            #pragma unroll
            for (int i = 0; i < 4; ++i)
                a[i] = *(const bf16x8*)(As + s * 4096 + (mBase + i * 16 + fr) * 32 + fk);
            #pragma unroll
            for (int j = 0; j < 4; ++j)
                b[j] = *(const bf16x8*)(Bs + s * 4096 + (nBase + j * 16 + fr) * 32 + fk);

            #pragma unroll
            for (int i = 0; i < 4; ++i)
                #pragma unroll
                for (int j = 0; j < 4; ++j)
                    acc[i][j] = __builtin_amdgcn_mfma_f32_16x16x32_bf16(a[i], b[j], acc[i][j], 0, 0, 0);
        }

        __syncthreads();
    }

    // ---- fused LSTM gate epilogue -------------------------------------
    // Physical col of acc[i][k][r] = tileN*128 + nBase + 16k + (lane&15);
    // with the W-row permutation: gate = k, logical j = 16*q + (lane&15),
    // q = tileN*2 + (wave&1).
    const int j = ((tileN * 2 + (wave & 1)) << 4) | (lane & 15);
    const float bi = bh[j];
    const float bf = bh[j + 1024];
    const float bg = bh[j + 2048];
    const float bo = bh[j + 3072];

    const int row0 = tileM * 128 + mBase + (lane >> 4) * 4;

    // batch all c loads first: one latency exposure, not 16 serialized ones
    float cv[4][4];
    #pragma unroll
    for (int i = 0; i < 4; ++i)
        #pragma unroll
        for (int r = 0; r < 4; ++r)
            cv[i][r] = c[(size_t)(row0 + i * 16 + r) * KH + j];

    #pragma unroll
    for (int i = 0; i < 4; ++i) {
        #pragma unroll
        for (int r = 0; r < 4; ++r) {
            const size_t idx = (size_t)(row0 + i * 16 + r) * KH + j;
            float iv = fsig(acc[i][0][r] + bi);
            float fv = fsig(acc[i][1][r] + bf);
            float gv = ftanh(acc[i][2][r] + bg);
            float ov = fsig(acc[i][3][r] + bo);
            float cn = fv * cv[i][r] + iv * gv;
            float hn = ov * ftanh(cn);
            out[idx] = hn;
            out[(size_t)ARR_ELEMS + idx] = cn;
        }
    }
}

// ----------------------------------------------------------------- launch ---
extern "C" void kernel_launch(void* const* d_in, const int* in_sizes, int n_in,
                              void* d_out, int out_size, void* d_ws, size_t ws_size,
                              hipStream_t stream) {
    const float* x  = (const float*)d_in[0];
    const float* h  = (const float*)d_in[1];
    const float* c  = (const float*)d_in[2];
    const float* Wh = (const float*)d_in[3];
    const float* bh = (const float*)d_in[4];
    const float* Wx = (const float*)d_in[5];
    float* out = (float*)d_out;

    unsigned short* ws   = (unsigned short*)d_ws;
    unsigned short* Acat = ws;                            // [4096 x 2048] bf16
    unsigned short* Wcat = ws + 2 * (size_t)ARR_ELEMS;    // [4096 x 2048] bf16 (rows permuted)

    convert_kernel<<<16384, 256, 0, stream>>>(h, x, Wh, Wx, Acat, Wcat);
    dim3 grid(32, 32);
    gemm_kernel<<<grid, 256, 0, stream>>>(Acat, Wcat, bh, c, out);
}